// Round 9
// baseline (318.841 us; speedup 1.0000x reference)
//
#include <hip/hip_runtime.h>

// HeteroGraphSage on MI355X — round 19: 1024-thread acct blocks (512 rows).
// R18 counters: acct 88us, occ 30% despite 24-wave theoretical 75% -> the
// time-weighted occupancy is dragged by a wave-quantization tail (782 blocks
// at 3/CU = 768 resident + 14 stragglers ~= half the kernel duration).
// 1024-thr blocks: 48KB LDS -> 2 blocks/CU (96KB<160KB), 32 waves/CU = HW
// max, grid 391 <= 512 resident slots -> ONE co-resident round, zero tail.
// Pipeline: memset(cursor) -> [prep|cvt|scatter] -> acct. 3 dispatches.
//   neigh64[a] = sum_e w_e * x_m[src_e] ; sumw[a] = sum_e w_e
//   h_a = relu( Wcomb @ [x_a | neigh64] + sumw*vbr + beff )
//   out = sigmoid(Wo . h_a + bo)
// Lessons: R8/R9/R16 — cursor atomics need XCD partition (>=26us); R10 —
// harness fill ~60us fixed; R11 — capacity-32 buckets == exact CSR; R12 —
// ILP-batch edges; R15 — NT streaming neutral; R17 — scatter at structural
// floor (~68us), stop tuning; R18 — gather fused into acct (-23us net),
// gather xmbf reads are L3-absorbed.
// Pre-commit: if acct >= 75us, tail/waves wasn't the limiter -> prefetch
// edge records to LDS in a block phase next.

typedef __attribute__((ext_vector_type(8))) short short8;
typedef __attribute__((ext_vector_type(4))) float f32x4;

#define PSH 12   // accounts-per-chunk shift for XCD partitioning (4096)
#define CAP 32   // bucket capacity (max observed degree ~19; P(>=32) ~ 1e-15/row)

__device__ inline unsigned short f32_bf16(float f) {
  unsigned int u = __float_as_uint(f);
  u += 0x7FFF + ((u >> 16) & 1);   // round-to-nearest-even
  return (unsigned short)(u >> 16);
}
__device__ inline unsigned int pk_bf16(float a, float b) {
  return (unsigned int)f32_bf16(a) | ((unsigned int)f32_bf16(b) << 16);
}
__device__ inline void fma8(float wE, uint4 v, float* a) {
  a[0] += wE * __uint_as_float(v.x << 16);
  a[1] += wE * __uint_as_float(v.x & 0xffff0000u);
  a[2] += wE * __uint_as_float(v.y << 16);
  a[3] += wE * __uint_as_float(v.y & 0xffff0000u);
  a[4] += wE * __uint_as_float(v.z << 16);
  a[5] += wE * __uint_as_float(v.z & 0xffff0000u);
  a[6] += wE * __uint_as_float(v.w << 16);
  a[7] += wE * __uint_as_float(v.w & 0xffff0000u);
}

// ---- merged front-end: [prep | cvt_xm | scatter] by blockIdx range ---------
// record: [wq:15b << 17 | src:17b]; w in [0,1) -> q=w*32768, err <= 3e-5.
__global__ __launch_bounds__(256) void setup_kernel(
    const float* __restrict__ xm, unsigned int* __restrict__ xmbf, int nq,
    const int* __restrict__ src, const int* __restrict__ dst,
    const float* __restrict__ w, int* __restrict__ cursor,
    unsigned int* __restrict__ edges, int E,
    const float* __restrict__ Wp_a, const float* __restrict__ bp_a,
    const float* __restrict__ Wr_ma, const float* __restrict__ br_ma,
    const float* __restrict__ Wc_a, const float* __restrict__ bc_a,
    unsigned short* __restrict__ Wcomb, float* __restrict__ beff,
    float* __restrict__ vbr, int nb_cvt) {
  __shared__ float wc_s[256];
  int b = blockIdx.x;
  int t = threadIdx.x;
  if (b < 128) {
    // ---- prep: fold Wc_a @ [Wp_a ; Wr_ma] into Wcomb[128][192] bf16 -------
    int col = b;
    wc_s[t] = Wc_a[col * 256 + t];
    __syncthreads();
    int wave = t >> 6, lane = t & 63;
    if (wave < 2) {
      int k = t;   // 0..127
      float acc = 0.f;
#pragma unroll
      for (int j = 0; j < 128; j += 4) {
        float a0 = Wp_a[(j + 0) * 128 + k];
        float a1 = Wp_a[(j + 1) * 128 + k];
        float a2 = Wp_a[(j + 2) * 128 + k];
        float a3 = Wp_a[(j + 3) * 128 + k];
        acc += wc_s[j] * a0 + wc_s[j + 1] * a1 + wc_s[j + 2] * a2 + wc_s[j + 3] * a3;
      }
      Wcomb[col * 192 + k] = f32_bf16(acc);
    } else if (wave == 2) {
      int kk = lane;   // 0..63
      float acc = 0.f;
#pragma unroll
      for (int j = 0; j < 128; j += 4) {
        float a0 = Wr_ma[(j + 0) * 64 + kk];
        float a1 = Wr_ma[(j + 1) * 64 + kk];
        float a2 = Wr_ma[(j + 2) * 64 + kk];
        float a3 = Wr_ma[(j + 3) * 64 + kk];
        acc += wc_s[128 + j] * a0 + wc_s[129 + j] * a1 + wc_s[130 + j] * a2 + wc_s[131 + j] * a3;
      }
      Wcomb[col * 192 + 128 + kk] = f32_bf16(acc);
    } else {
      float v1 = wc_s[lane] * bp_a[lane] + wc_s[lane + 64] * bp_a[lane + 64];
      float v2 = wc_s[128 + lane] * br_ma[lane] + wc_s[192 + lane] * br_ma[lane + 64];
#pragma unroll
      for (int m = 1; m <= 32; m <<= 1) {
        v1 += __shfl_xor(v1, m, 64);
        v2 += __shfl_xor(v2, m, 64);
      }
      if (lane == 0) { beff[col] = v1 + bc_a[col]; vbr[col] = v2; }
    }
    return;
  }
  b -= 128;
  if (b < nb_cvt) {
    // ---- cvt: x_merchant f32 -> packed bf16 pairs, float4-vectorized ------
    int i = b * 256 + t;
    if (i < nq) {
      float4 v = ((const float4*)xm)[i];
      ((uint2*)xmbf)[i] = make_uint2(pk_bf16(v.x, v.y), pk_bf16(v.z, v.w));
    }
    return;
  }
  b -= nb_cvt;
  // ---- scatter: XCD-partitioned, 16 edges/thread, speculative vec loads --
  int slice = b >> 3;
  int p = b & 7;
  int e0 = slice * 4096 + t * 16;
  if (e0 >= E) return;
  if (e0 + 16 <= E) {
    int dv[16], sv[16];
    float wv[16];
#pragma unroll
    for (int q = 0; q < 4; ++q) {
      int4 dq = ((const int4*)(dst + e0))[q];
      int4 sq = ((const int4*)(src + e0))[q];
      float4 wq = ((const float4*)(w + e0))[q];
      dv[q * 4 + 0] = dq.x; dv[q * 4 + 1] = dq.y; dv[q * 4 + 2] = dq.z; dv[q * 4 + 3] = dq.w;
      sv[q * 4 + 0] = sq.x; sv[q * 4 + 1] = sq.y; sv[q * 4 + 2] = sq.z; sv[q * 4 + 3] = sq.w;
      wv[q * 4 + 0] = wq.x; wv[q * 4 + 1] = wq.y; wv[q * 4 + 2] = wq.z; wv[q * 4 + 3] = wq.w;
    }
    unsigned int rec[16];
#pragma unroll
    for (int k = 0; k < 16; ++k) {
      unsigned int q = (unsigned int)fminf(wv[k] * 32768.0f, 32767.0f);
      rec[k] = (unsigned int)sv[k] | (q << 17);
    }
#pragma unroll
    for (int k = 0; k < 16; ++k) {
      int d = dv[k];
      if (((d >> PSH) & 7) != p) continue;
      int idx = atomicAdd(&cursor[d], 1);
      if (idx < CAP) edges[((size_t)d << 5) + idx] = rec[k];
    }
  } else {
    for (int k = 0; k < 16 && e0 + k < E; ++k) {
      int e = e0 + k;
      int d = dst[e];
      if (((d >> PSH) & 7) != p) continue;
      int idx = atomicAdd(&cursor[d], 1);
      if (idx < CAP) {
        unsigned int q = (unsigned int)fminf(w[e] * 32768.0f, 32767.0f);
        edges[((size_t)d << 5) + idx] = (unsigned int)src[e] | (q << 17);
      }
    }
  }
}

// ---- fused gather + account GEMM + head: 1024 threads, 512 rows/block ------
__global__ __launch_bounds__(1024) void acct_kernel(
    const float* __restrict__ xa, const unsigned int* __restrict__ xmbf,
    const unsigned int* __restrict__ edges, const int* __restrict__ cursor,
    const unsigned int* __restrict__ Wcomb32,
    const float* __restrict__ beff, const float* __restrict__ vbr,
    const float* __restrict__ Wo, const float* __restrict__ bo,
    float* __restrict__ out, int NA) {
  __shared__ unsigned int B_lds[24 * 128 * 4];   // 48 KB
  int tid = threadIdx.x;
#pragma unroll
  for (int it = 0; it < 3; ++it) {
    int i = tid + it * 1024;
    int c = i >> 7, col = i & 127;
    uint4 v = ((const uint4*)Wcomb32)[col * 24 + c];
    *((uint4*)&B_lds[i * 4]) = v;
  }
  __syncthreads();

  int wave = tid >> 6, lane = tid & 63;
  int n15 = lane & 15, quad = lane >> 4;
  float bo0 = bo[0];
  const float wscale = 1.0f / 32768.0f;

  union U4 { uint4 u; short8 h; };

#pragma unroll
  for (int tile = 0; tile < 2; ++tile) {
    int rowbase = blockIdx.x * 512 + (wave * 2 + tile) * 16;
    int m = rowbase + n15;
    int mc = min(m, NA - 1);

    // ---- in-register gather for row mc: quad-lanes split 64 feats --------
    int cnt = min(cursor[mc], CAP);
    const unsigned int* eb = edges + ((size_t)mc << 5);
    uint4 r0 = ((const uint4*)eb)[0];
    uint4 r1 = ((const uint4*)eb)[1];
    unsigned int recs[8] = {r0.x, r0.y, r0.z, r0.w, r1.x, r1.y, r1.z, r1.w};
    float accA[8] = {0.f, 0.f, 0.f, 0.f, 0.f, 0.f, 0.f, 0.f};
    float accB[8] = {0.f, 0.f, 0.f, 0.f, 0.f, 0.f, 0.f, 0.f};
    float wsum = 0.f;
#pragma unroll
    for (int e = 0; e < 8; ++e) {
      if (e < cnt) {
        unsigned int pr = recs[e];
        float wE = (float)(pr >> 17) * wscale;
        const uint4* xr = (const uint4*)(xmbf + (size_t)(pr & 0x1ffffu) * 32);
        uint4 va = xr[quad];
        uint4 vb = xr[quad + 4];
        wsum += wE;
        fma8(wE, va, accA);
        fma8(wE, vb, accB);
      }
    }
    for (int e = 8; e < cnt; ++e) {   // rare Poisson tail (P ~ 7%)
      unsigned int pr = eb[e];
      float wE = (float)(pr >> 17) * wscale;
      const uint4* xr = (const uint4*)(xmbf + (size_t)(pr & 0x1ffffu) * 32);
      uint4 va = xr[quad];
      uint4 vb = xr[quad + 4];
      wsum += wE;
      fma8(wE, va, accA);
      fma8(wE, vb, accB);
    }

    U4 afr[6];
    afr[4].u = make_uint4(pk_bf16(accA[0], accA[1]), pk_bf16(accA[2], accA[3]),
                          pk_bf16(accA[4], accA[5]), pk_bf16(accA[6], accA[7]));
    afr[5].u = make_uint4(pk_bf16(accB[0], accB[1]), pk_bf16(accB[2], accB[3]),
                          pk_bf16(accB[4], accB[5]), pk_bf16(accB[6], accB[7]));

    const float* xrow = xa + (size_t)mc * 128 + quad * 8;
#pragma unroll
    for (int s = 0; s < 4; ++s) {
      float4 f0 = ((const float4*)(xrow + s * 32))[0];
      float4 f1 = ((const float4*)(xrow + s * 32))[1];
      afr[s].u = make_uint4(pk_bf16(f0.x, f0.y), pk_bf16(f0.z, f0.w),
                            pk_bf16(f1.x, f1.y), pk_bf16(f1.z, f1.w));
    }

    f32x4 acc[8];
#pragma unroll
    for (int t = 0; t < 8; ++t) acc[t] = (f32x4){0.f, 0.f, 0.f, 0.f};

#pragma unroll
    for (int s = 0; s < 6; ++s) {
#pragma unroll
      for (int t = 0; t < 8; ++t) {
        U4 bfr;
        bfr.u = *((const uint4*)&B_lds[((s * 4 + quad) * 128 + t * 16 + n15) * 4]);
        acc[t] = __builtin_amdgcn_mfma_f32_16x16x32_bf16(afr[s].h, bfr.h, acc[t], 0, 0, 0);
      }
    }

    float sw[4];
#pragma unroll
    for (int r = 0; r < 4; ++r) sw[r] = __shfl(wsum, quad * 4 + r, 64);

    float rowsum[4] = {0.f, 0.f, 0.f, 0.f};
#pragma unroll
    for (int t = 0; t < 8; ++t) {
      int col = t * 16 + n15;
      float be = beff[col], vb = vbr[col], wo = Wo[col];
#pragma unroll
      for (int r = 0; r < 4; ++r) {
        float h = acc[t][r] + be + sw[r] * vb;
        h = fmaxf(h, 0.f);
        rowsum[r] += h * wo;
      }
    }
#pragma unroll
    for (int msk = 1; msk <= 8; msk <<= 1) {
#pragma unroll
      for (int r = 0; r < 4; ++r) rowsum[r] += __shfl_xor(rowsum[r], msk, 64);
    }
    if (n15 == 0) {
#pragma unroll
      for (int r = 0; r < 4; ++r) {
        int grow = rowbase + quad * 4 + r;
        if (grow < NA) out[grow] = 1.0f / (1.0f + __expf(-(rowsum[r] + bo0)));
      }
    }
  }
}

extern "C" void kernel_launch(void* const* d_in, const int* in_sizes, int n_in,
                              void* d_out, int out_size, void* d_ws, size_t ws_size,
                              hipStream_t stream) {
  const float* xa      = (const float*)d_in[0];
  const float* xm      = (const float*)d_in[1];
  const int*   ema_src = (const int*)d_in[5];
  const int*   ema_dst = (const int*)d_in[6];
  const float* ema_w   = (const float*)d_in[7];
  const float* Wp_a    = (const float*)d_in[8];
  const float* bp_a    = (const float*)d_in[9];
  const float* Wr_ma   = (const float*)d_in[14];
  const float* br_ma   = (const float*)d_in[15];
  const float* Wc_a    = (const float*)d_in[16];
  const float* bc_a    = (const float*)d_in[17];
  const float* Wo      = (const float*)d_in[20];
  const float* bo      = (const float*)d_in[21];

  int NA = in_sizes[0] / 128;
  int NM = in_sizes[1] / 64;
  int E  = in_sizes[5];

  char* ws = (char*)d_ws;
  size_t off = 0;
  auto take = [&](size_t bytes) { char* p = ws + off; off = (off + bytes + 255) & ~(size_t)255; return p; };
  unsigned int* xmbf    = (unsigned int*)take((size_t)NM * 32 * 4);      // bf16 pairs [NM][32]
  int* cursor           = (int*)take((size_t)NA * 4);
  unsigned int* edges   = (unsigned int*)take((size_t)NA * CAP * 4);     // capacity-32 buckets
  unsigned short* Wcomb = (unsigned short*)take(128 * 192 * 2);
  float* beff           = (float*)take(128 * 4);
  float* vbr            = (float*)take(128 * 4);

  hipMemsetAsync(cursor, 0, (size_t)NA * 4, stream);

  int nq = NM * 16;                       // float4 groups in x_merchant
  int nb_cvt = (nq + 255) / 256;
  int nb_sc  = ((E + 4095) / 4096) * 8;   // 16 edges/thread, 8-way partitioned
  setup_kernel<<<128 + nb_cvt + nb_sc, 256, 0, stream>>>(
      xm, xmbf, nq, ema_src, ema_dst, ema_w, cursor, edges, E,
      Wp_a, bp_a, Wr_ma, br_ma, Wc_a, bc_a, Wcomb, beff, vbr, nb_cvt);

  int ab = (NA + 511) / 512;
  acct_kernel<<<ab, 1024, 0, stream>>>(xa, xmbf, edges, cursor,
                                       (const unsigned int*)Wcomb,
                                       beff, vbr, Wo, bo, (float*)d_out, NA);
}

// Round 10
// 316.857 us; speedup vs baseline: 1.0063x; 1.0063x over previous
//
#include <hip/hip_runtime.h>

// HeteroGraphSage on MI355X — round 20: hoisted edge loads (issue-early /
// consume-late) + revert acct to 512 threads. R19 pre-commit fired (1024-thr
// made acct WORSE, 88->95us): the limiter is the per-tile serial chain
// cursor -> edges(~600cy) -> scattered xmbf(~500cy) -> pack -> MFMA.
// Fix: issue cursor+edge-bucket loads for BOTH tiles at kernel entry, before
// the B_lds fill + barrier — they complete under the fill. Each tile then
// starts directly at the xmbf batch; xa float4 loads moved ahead of the
// gather loop so they fly in parallel with the scattered loads.
// Pipeline: memset(cursor) -> [prep|cvt|scatter] -> acct. 3 dispatches.
//   neigh64[a] = sum_e w_e * x_m[src_e] ; sumw[a] = sum_e w_e
//   h_a = relu( Wcomb @ [x_a | neigh64] + sumw*vbr + beff )
//   out = sigmoid(Wo . h_a + bo)
// Lessons: R8/R9/R16 — cursor atomics need XCD partition (>=26us); R10 —
// harness fill ~60us fixed; R11 — capacity-32 buckets == exact CSR; R15 —
// NT streaming neutral; R17 — scatter at structural floor (~68us); R18 —
// gather fused into acct (-23us); R19 — 1024-thr blocks regress (TLP
// granularity > residency), occupancy counter not the lever.
// Pre-commit: if acct >= 82us, latency hoisting is exhausted -> next round
// pre-convert xa to bf16 in setup (halve acct stream traffic).

typedef __attribute__((ext_vector_type(8))) short short8;
typedef __attribute__((ext_vector_type(4))) float f32x4;

#define PSH 12   // accounts-per-chunk shift for XCD partitioning (4096)
#define CAP 32   // bucket capacity (max observed degree ~19; P(>=32) ~ 1e-15/row)

__device__ inline unsigned short f32_bf16(float f) {
  unsigned int u = __float_as_uint(f);
  u += 0x7FFF + ((u >> 16) & 1);   // round-to-nearest-even
  return (unsigned short)(u >> 16);
}
__device__ inline unsigned int pk_bf16(float a, float b) {
  return (unsigned int)f32_bf16(a) | ((unsigned int)f32_bf16(b) << 16);
}
__device__ inline void fma8(float wE, uint4 v, float* a) {
  a[0] += wE * __uint_as_float(v.x << 16);
  a[1] += wE * __uint_as_float(v.x & 0xffff0000u);
  a[2] += wE * __uint_as_float(v.y << 16);
  a[3] += wE * __uint_as_float(v.y & 0xffff0000u);
  a[4] += wE * __uint_as_float(v.z << 16);
  a[5] += wE * __uint_as_float(v.z & 0xffff0000u);
  a[6] += wE * __uint_as_float(v.w << 16);
  a[7] += wE * __uint_as_float(v.w & 0xffff0000u);
}

// ---- merged front-end: [prep | cvt_xm | scatter] by blockIdx range ---------
// record: [wq:15b << 17 | src:17b]; w in [0,1) -> q=w*32768, err <= 3e-5.
__global__ __launch_bounds__(256) void setup_kernel(
    const float* __restrict__ xm, unsigned int* __restrict__ xmbf, int nq,
    const int* __restrict__ src, const int* __restrict__ dst,
    const float* __restrict__ w, int* __restrict__ cursor,
    unsigned int* __restrict__ edges, int E,
    const float* __restrict__ Wp_a, const float* __restrict__ bp_a,
    const float* __restrict__ Wr_ma, const float* __restrict__ br_ma,
    const float* __restrict__ Wc_a, const float* __restrict__ bc_a,
    unsigned short* __restrict__ Wcomb, float* __restrict__ beff,
    float* __restrict__ vbr, int nb_cvt) {
  __shared__ float wc_s[256];
  int b = blockIdx.x;
  int t = threadIdx.x;
  if (b < 128) {
    // ---- prep: fold Wc_a @ [Wp_a ; Wr_ma] into Wcomb[128][192] bf16 -------
    int col = b;
    wc_s[t] = Wc_a[col * 256 + t];
    __syncthreads();
    int wave = t >> 6, lane = t & 63;
    if (wave < 2) {
      int k = t;   // 0..127
      float acc = 0.f;
#pragma unroll
      for (int j = 0; j < 128; j += 4) {
        float a0 = Wp_a[(j + 0) * 128 + k];
        float a1 = Wp_a[(j + 1) * 128 + k];
        float a2 = Wp_a[(j + 2) * 128 + k];
        float a3 = Wp_a[(j + 3) * 128 + k];
        acc += wc_s[j] * a0 + wc_s[j + 1] * a1 + wc_s[j + 2] * a2 + wc_s[j + 3] * a3;
      }
      Wcomb[col * 192 + k] = f32_bf16(acc);
    } else if (wave == 2) {
      int kk = lane;   // 0..63
      float acc = 0.f;
#pragma unroll
      for (int j = 0; j < 128; j += 4) {
        float a0 = Wr_ma[(j + 0) * 64 + kk];
        float a1 = Wr_ma[(j + 1) * 64 + kk];
        float a2 = Wr_ma[(j + 2) * 64 + kk];
        float a3 = Wr_ma[(j + 3) * 64 + kk];
        acc += wc_s[128 + j] * a0 + wc_s[129 + j] * a1 + wc_s[130 + j] * a2 + wc_s[131 + j] * a3;
      }
      Wcomb[col * 192 + 128 + kk] = f32_bf16(acc);
    } else {
      float v1 = wc_s[lane] * bp_a[lane] + wc_s[lane + 64] * bp_a[lane + 64];
      float v2 = wc_s[128 + lane] * br_ma[lane] + wc_s[192 + lane] * br_ma[lane + 64];
#pragma unroll
      for (int m = 1; m <= 32; m <<= 1) {
        v1 += __shfl_xor(v1, m, 64);
        v2 += __shfl_xor(v2, m, 64);
      }
      if (lane == 0) { beff[col] = v1 + bc_a[col]; vbr[col] = v2; }
    }
    return;
  }
  b -= 128;
  if (b < nb_cvt) {
    // ---- cvt: x_merchant f32 -> packed bf16 pairs, float4-vectorized ------
    int i = b * 256 + t;
    if (i < nq) {
      float4 v = ((const float4*)xm)[i];
      ((uint2*)xmbf)[i] = make_uint2(pk_bf16(v.x, v.y), pk_bf16(v.z, v.w));
    }
    return;
  }
  b -= nb_cvt;
  // ---- scatter: XCD-partitioned, 16 edges/thread, speculative vec loads --
  int slice = b >> 3;
  int p = b & 7;
  int e0 = slice * 4096 + t * 16;
  if (e0 >= E) return;
  if (e0 + 16 <= E) {
    int dv[16], sv[16];
    float wv[16];
#pragma unroll
    for (int q = 0; q < 4; ++q) {
      int4 dq = ((const int4*)(dst + e0))[q];
      int4 sq = ((const int4*)(src + e0))[q];
      float4 wq = ((const float4*)(w + e0))[q];
      dv[q * 4 + 0] = dq.x; dv[q * 4 + 1] = dq.y; dv[q * 4 + 2] = dq.z; dv[q * 4 + 3] = dq.w;
      sv[q * 4 + 0] = sq.x; sv[q * 4 + 1] = sq.y; sv[q * 4 + 2] = sq.z; sv[q * 4 + 3] = sq.w;
      wv[q * 4 + 0] = wq.x; wv[q * 4 + 1] = wq.y; wv[q * 4 + 2] = wq.z; wv[q * 4 + 3] = wq.w;
    }
    unsigned int rec[16];
#pragma unroll
    for (int k = 0; k < 16; ++k) {
      unsigned int q = (unsigned int)fminf(wv[k] * 32768.0f, 32767.0f);
      rec[k] = (unsigned int)sv[k] | (q << 17);
    }
#pragma unroll
    for (int k = 0; k < 16; ++k) {
      int d = dv[k];
      if (((d >> PSH) & 7) != p) continue;
      int idx = atomicAdd(&cursor[d], 1);
      if (idx < CAP) edges[((size_t)d << 5) + idx] = rec[k];
    }
  } else {
    for (int k = 0; k < 16 && e0 + k < E; ++k) {
      int e = e0 + k;
      int d = dst[e];
      if (((d >> PSH) & 7) != p) continue;
      int idx = atomicAdd(&cursor[d], 1);
      if (idx < CAP) {
        unsigned int q = (unsigned int)fminf(w[e] * 32768.0f, 32767.0f);
        edges[((size_t)d << 5) + idx] = (unsigned int)src[e] | (q << 17);
      }
    }
  }
}

// ---- fused gather + account GEMM + head: 512 threads, 256 rows/block -------
__global__ __launch_bounds__(512) void acct_kernel(
    const float* __restrict__ xa, const unsigned int* __restrict__ xmbf,
    const unsigned int* __restrict__ edges, const int* __restrict__ cursor,
    const unsigned int* __restrict__ Wcomb32,
    const float* __restrict__ beff, const float* __restrict__ vbr,
    const float* __restrict__ Wo, const float* __restrict__ bo,
    float* __restrict__ out, int NA) {
  __shared__ unsigned int B_lds[24 * 128 * 4];   // 48 KB
  int tid = threadIdx.x;
  int wave = tid >> 6, lane = tid & 63;
  int n15 = lane & 15, quad = lane >> 4;

  // ---- hoisted edge-stage loads for BOTH tiles (issue before LDS fill) ----
  int mc0, mc1, cnt0, cnt1;
  uint4 e0a, e0b, e1a, e1b;
  {
    int rowbase0 = blockIdx.x * 256 + (wave * 2 + 0) * 16;
    int rowbase1 = blockIdx.x * 256 + (wave * 2 + 1) * 16;
    mc0 = min(rowbase0 + n15, NA - 1);
    mc1 = min(rowbase1 + n15, NA - 1);
    cnt0 = min(cursor[mc0], CAP);
    cnt1 = min(cursor[mc1], CAP);
    const uint4* eb0 = (const uint4*)(edges + ((size_t)mc0 << 5));
    const uint4* eb1 = (const uint4*)(edges + ((size_t)mc1 << 5));
    e0a = eb0[0]; e0b = eb0[1];
    e1a = eb1[0]; e1b = eb1[1];
  }

#pragma unroll
  for (int it = 0; it < 6; ++it) {
    int i = tid + it * 512;
    int c = i >> 7, col = i & 127;
    uint4 v = ((const uint4*)Wcomb32)[col * 24 + c];
    *((uint4*)&B_lds[i * 4]) = v;
  }
  __syncthreads();

  float bo0 = bo[0];
  const float wscale = 1.0f / 32768.0f;

  union U4 { uint4 u; short8 h; };

#pragma unroll
  for (int tile = 0; tile < 2; ++tile) {
    int rowbase = blockIdx.x * 256 + (wave * 2 + tile) * 16;
    int mc = (tile == 0) ? mc0 : mc1;
    int cnt = (tile == 0) ? cnt0 : cnt1;
    uint4 ra = (tile == 0) ? e0a : e1a;
    uint4 rb = (tile == 0) ? e0b : e1b;

    // ---- xa stream loads FIRST: fly in parallel with the scattered gather -
    const float* xrow = xa + (size_t)mc * 128 + quad * 8;
    float4 xf[8];
#pragma unroll
    for (int s = 0; s < 4; ++s) {
      xf[s * 2 + 0] = ((const float4*)(xrow + s * 32))[0];
      xf[s * 2 + 1] = ((const float4*)(xrow + s * 32))[1];
    }

    // ---- in-register gather: recs already resident (hoisted) --------------
    unsigned int recs[8] = {ra.x, ra.y, ra.z, ra.w, rb.x, rb.y, rb.z, rb.w};
    float accA[8] = {0.f, 0.f, 0.f, 0.f, 0.f, 0.f, 0.f, 0.f};
    float accB[8] = {0.f, 0.f, 0.f, 0.f, 0.f, 0.f, 0.f, 0.f};
    float wsum = 0.f;
#pragma unroll
    for (int e = 0; e < 8; ++e) {
      if (e < cnt) {
        unsigned int pr = recs[e];
        float wE = (float)(pr >> 17) * wscale;
        const uint4* xr = (const uint4*)(xmbf + (size_t)(pr & 0x1ffffu) * 32);
        uint4 va = xr[quad];
        uint4 vb = xr[quad + 4];
        wsum += wE;
        fma8(wE, va, accA);
        fma8(wE, vb, accB);
      }
    }
    const unsigned int* eb = edges + ((size_t)mc << 5);
    for (int e = 8; e < cnt; ++e) {   // rare Poisson tail (P ~ 7%)
      unsigned int pr = eb[e];
      float wE = (float)(pr >> 17) * wscale;
      const uint4* xr = (const uint4*)(xmbf + (size_t)(pr & 0x1ffffu) * 32);
      uint4 va = xr[quad];
      uint4 vb = xr[quad + 4];
      wsum += wE;
      fma8(wE, va, accA);
      fma8(wE, vb, accB);
    }

    U4 afr[6];
#pragma unroll
    for (int s = 0; s < 4; ++s) {
      float4 f0 = xf[s * 2 + 0];
      float4 f1 = xf[s * 2 + 1];
      afr[s].u = make_uint4(pk_bf16(f0.x, f0.y), pk_bf16(f0.z, f0.w),
                            pk_bf16(f1.x, f1.y), pk_bf16(f1.z, f1.w));
    }
    afr[4].u = make_uint4(pk_bf16(accA[0], accA[1]), pk_bf16(accA[2], accA[3]),
                          pk_bf16(accA[4], accA[5]), pk_bf16(accA[6], accA[7]));
    afr[5].u = make_uint4(pk_bf16(accB[0], accB[1]), pk_bf16(accB[2], accB[3]),
                          pk_bf16(accB[4], accB[5]), pk_bf16(accB[6], accB[7]));

    f32x4 acc[8];
#pragma unroll
    for (int t = 0; t < 8; ++t) acc[t] = (f32x4){0.f, 0.f, 0.f, 0.f};

#pragma unroll
    for (int s = 0; s < 6; ++s) {
#pragma unroll
      for (int t = 0; t < 8; ++t) {
        U4 bfr;
        bfr.u = *((const uint4*)&B_lds[((s * 4 + quad) * 128 + t * 16 + n15) * 4]);
        acc[t] = __builtin_amdgcn_mfma_f32_16x16x32_bf16(afr[s].h, bfr.h, acc[t], 0, 0, 0);
      }
    }

    float sw[4];
#pragma unroll
    for (int r = 0; r < 4; ++r) sw[r] = __shfl(wsum, quad * 4 + r, 64);

    float rowsum[4] = {0.f, 0.f, 0.f, 0.f};
#pragma unroll
    for (int t = 0; t < 8; ++t) {
      int col = t * 16 + n15;
      float be = beff[col], vb = vbr[col], wo = Wo[col];
#pragma unroll
      for (int r = 0; r < 4; ++r) {
        float h = acc[t][r] + be + sw[r] * vb;
        h = fmaxf(h, 0.f);
        rowsum[r] += h * wo;
      }
    }
#pragma unroll
    for (int msk = 1; msk <= 8; msk <<= 1) {
#pragma unroll
      for (int r = 0; r < 4; ++r) rowsum[r] += __shfl_xor(rowsum[r], msk, 64);
    }
    if (n15 == 0) {
#pragma unroll
      for (int r = 0; r < 4; ++r) {
        int grow = rowbase + quad * 4 + r;
        if (grow < NA) out[grow] = 1.0f / (1.0f + __expf(-(rowsum[r] + bo0)));
      }
    }
  }
}

extern "C" void kernel_launch(void* const* d_in, const int* in_sizes, int n_in,
                              void* d_out, int out_size, void* d_ws, size_t ws_size,
                              hipStream_t stream) {
  const float* xa      = (const float*)d_in[0];
  const float* xm      = (const float*)d_in[1];
  const int*   ema_src = (const int*)d_in[5];
  const int*   ema_dst = (const int*)d_in[6];
  const float* ema_w   = (const float*)d_in[7];
  const float* Wp_a    = (const float*)d_in[8];
  const float* bp_a    = (const float*)d_in[9];
  const float* Wr_ma   = (const float*)d_in[14];
  const float* br_ma   = (const float*)d_in[15];
  const float* Wc_a    = (const float*)d_in[16];
  const float* bc_a    = (const float*)d_in[17];
  const float* Wo      = (const float*)d_in[20];
  const float* bo      = (const float*)d_in[21];

  int NA = in_sizes[0] / 128;
  int NM = in_sizes[1] / 64;
  int E  = in_sizes[5];

  char* ws = (char*)d_ws;
  size_t off = 0;
  auto take = [&](size_t bytes) { char* p = ws + off; off = (off + bytes + 255) & ~(size_t)255; return p; };
  unsigned int* xmbf    = (unsigned int*)take((size_t)NM * 32 * 4);      // bf16 pairs [NM][32]
  int* cursor           = (int*)take((size_t)NA * 4);
  unsigned int* edges   = (unsigned int*)take((size_t)NA * CAP * 4);     // capacity-32 buckets
  unsigned short* Wcomb = (unsigned short*)take(128 * 192 * 2);
  float* beff           = (float*)take(128 * 4);
  float* vbr            = (float*)take(128 * 4);

  hipMemsetAsync(cursor, 0, (size_t)NA * 4, stream);

  int nq = NM * 16;                       // float4 groups in x_merchant
  int nb_cvt = (nq + 255) / 256;
  int nb_sc  = ((E + 4095) / 4096) * 8;   // 16 edges/thread, 8-way partitioned
  setup_kernel<<<128 + nb_cvt + nb_sc, 256, 0, stream>>>(
      xm, xmbf, nq, ema_src, ema_dst, ema_w, cursor, edges, E,
      Wp_a, bp_a, Wr_ma, br_ma, Wc_a, bc_a, Wcomb, beff, vbr, nb_cvt);

  int ab = (NA + 255) / 256;
  acct_kernel<<<ab, 512, 0, stream>>>(xa, xmbf, edges, cursor,
                                      (const unsigned int*)Wcomb,
                                      beff, vbr, Wo, bo, (float*)d_out, NA);
}